// Round 1
// baseline (320.906 us; speedup 1.0000x reference)
//
#include <hip/hip_runtime.h>

// LaplacianPyramidLoss: loss = sum_l mean(|pyr(x)[l] - pyr(t)[l]|)
// Linearity: pyr(x)[l]-pyr(t)[l] = pyr(x-t)[l] -> build ONE pyramid of d=x-t.
// Per level: fused {blur@even-positions (=downsample), |cur - up(down)| L1 sum}.
// Level 0 fuses d=x-t into tile load; level 2 fuses the final mean(|down2|).

constexpr int THREADS = 256;
constexpr int TILE    = 32;            // down outputs per dim per block
constexpr int IN_T    = 2 * TILE + 3;  // 67: input tile incl. 5x5 stencil halo

template <bool FUSE_DIFF, bool LAST, bool WRITE_DOWN>
__global__ __launch_bounds__(THREADS)
void lap_level(const float* __restrict__ A,    // x (lvl0) or cur
               const float* __restrict__ Bp,   // t (lvl0) or nullptr
               const float* __restrict__ w25,  // 5x5 gaussian weights (channel 0)
               float* __restrict__ down,       // output H/2 x W/2 (if WRITE_DOWN)
               float* __restrict__ sums,       // sums[level], sums[3] for LAST
               int H, int W, int level)
{
    __shared__ float sd[IN_T * IN_T];  // stride 67 (odd) -> benign bank layout
    const int tid = threadIdx.x;
    const int ox0 = blockIdx.x * TILE;
    const int oy0 = blockIdx.y * TILE;
    const int n   = blockIdx.z;        // fused B*C image-channel index
    const size_t ibase = (size_t)n * H * W;
    const int gy0 = 2 * oy0 - 2;
    const int gx0 = 2 * ox0 - 2;

    // Stage input tile (zero-padded at borders). Each global elem read once.
    for (int idx = tid; idx < IN_T * IN_T; idx += THREADS) {
        const int r  = idx / IN_T;
        const int c  = idx - r * IN_T;
        const int gy = gy0 + r;
        const int gx = gx0 + c;
        float v = 0.0f;
        if (gy >= 0 && gy < H && gx >= 0 && gx < W) {
            const size_t o = ibase + (size_t)gy * W + gx;
            v = FUSE_DIFF ? (A[o] - Bp[o]) : A[o];
        }
        sd[idx] = v;
    }

    float w[25];
#pragma unroll
    for (int i = 0; i < 25; ++i) w[i] = w25[i];  // uniform -> scalar-cached

    __syncthreads();

    const int lx  = tid & (TILE - 1);  // 0..31
    const int ly0 = tid / TILE;        // 0..7
    const int Hd = H >> 1, Wd = W >> 1;
    float lsum = 0.0f;  // sum |cur - up(down)| over this thread's outputs
    float dsum = 0.0f;  // (LAST) sum |down|

#pragma unroll
    for (int k = 0; k < (TILE * TILE) / THREADS; ++k) {
        const int ly = ly0 + k * (THREADS / TILE);
        // down[oy0+ly][ox0+lx] needs cur rows 2(oy0+ly)-2.. -> local rows 2*ly..2*ly+4
        const float* row0 = &sd[(2 * ly) * IN_T + 2 * lx];
        float acc = 0.0f;
#pragma unroll
        for (int dy = 0; dy < 5; ++dy) {
#pragma unroll
            for (int dx = 0; dx < 5; ++dx)
                acc = fmaf(w[dy * 5 + dx], row0[dy * IN_T + dx], acc);
        }
        if (WRITE_DOWN)
            down[(size_t)n * Hd * Wd + (size_t)(oy0 + ly) * Wd + (ox0 + lx)] = acc;
        // cur pixels covered by this down value: local rows 2ly+2..3, cols 2lx+2..3
        lsum += fabsf(row0[2 * IN_T + 2] - acc)
              + fabsf(row0[2 * IN_T + 3] - acc)
              + fabsf(row0[3 * IN_T + 2] - acc)
              + fabsf(row0[3 * IN_T + 3] - acc);
        if (LAST) dsum += fabsf(acc);
    }

    // wave64 reduce, then cross-wave via LDS, one atomic per block per level
#pragma unroll
    for (int off = 32; off > 0; off >>= 1) {
        lsum += __shfl_down(lsum, off);
        if (LAST) dsum += __shfl_down(dsum, off);
    }
    __shared__ float wsum_l[THREADS / 64];
    __shared__ float wsum_d[THREADS / 64];
    const int wid = tid >> 6;
    if ((tid & 63) == 0) {
        wsum_l[wid] = lsum;
        if (LAST) wsum_d[wid] = dsum;
    }
    __syncthreads();
    if (tid == 0) {
        float s = 0.0f, s2 = 0.0f;
#pragma unroll
        for (int i = 0; i < THREADS / 64; ++i) {
            s += wsum_l[i];
            if (LAST) s2 += wsum_d[i];
        }
        atomicAdd(&sums[level], s);
        if (LAST) atomicAdd(&sums[3], s2);
    }
}

__global__ void finalize_kernel(const float* __restrict__ sums,
                                float* __restrict__ out,
                                float inv0, float inv1, float inv2, float inv3)
{
    out[0] = sums[0] * inv0 + sums[1] * inv1 + sums[2] * inv2 + sums[3] * inv3;
}

extern "C" void kernel_launch(void* const* d_in, const int* in_sizes, int n_in,
                              void* d_out, int out_size, void* d_ws, size_t ws_size,
                              hipStream_t stream)
{
    const float* x   = (const float*)d_in[0];
    const float* t   = (const float*)d_in[1];
    const float* ker = (const float*)d_in[2];  // (13,1,5,5); all channels identical
    float* out = (float*)d_out;

    constexpr int B = 16, C = 13, H = 512, W = 512;
    constexpr int N = B * C;  // 208 image-channels

    // workspace layout: [4 floats sums (pad 256B)] [down0: N*256*256] [down1: N*128*128]
    float* sums  = (float*)d_ws;
    float* down0 = (float*)((char*)d_ws + 256);
    float* down1 = down0 + (size_t)N * (H / 2) * (W / 2);

    hipMemsetAsync(sums, 0, 4 * sizeof(float), stream);

    dim3 blk(THREADS);
    // level 0: cur = x - t (fused), 512 -> down0 256
    lap_level<true, false, true><<<dim3((W/2)/TILE, (H/2)/TILE, N), blk, 0, stream>>>(
        x, t, ker, down0, sums, H, W, 0);
    // level 1: down0 256 -> down1 128
    lap_level<false, false, true><<<dim3((W/4)/TILE, (H/4)/TILE, N), blk, 0, stream>>>(
        down0, nullptr, ker, down1, sums, H / 2, W / 2, 1);
    // level 2: down1 128 -> (64, kept in-register), fuses level-3 mean(|down2|)
    lap_level<false, true, false><<<dim3((W/8)/TILE, (H/8)/TILE, N), blk, 0, stream>>>(
        down1, nullptr, ker, nullptr, sums, H / 4, W / 4, 2);

    const float inv0 = 1.0f / ((float)N * H * W);
    const float inv1 = 1.0f / ((float)N * (H/2) * (W/2));
    const float inv2 = 1.0f / ((float)N * (H/4) * (W/4));
    const float inv3 = 1.0f / ((float)N * (H/8) * (W/8));
    finalize_kernel<<<1, 1, 0, stream>>>(sums, out, inv0, inv1, inv2, inv3);
}

// Round 2
// 281.923 us; speedup vs baseline: 1.1383x; 1.1383x over previous
//
#include <hip/hip_runtime.h>

// LaplacianPyramidLoss: loss = sum_l mean(|pyr(x)[l] - pyr(t)[l]|)
// Linearity: pyr(x)[l]-pyr(t)[l] = pyr(x-t)[l] -> build ONE pyramid of d=x-t.
// Per level: fused {blur@even-positions (=downsample), |cur - up(down)| L1 sum}.
// Level 0 fuses d=x-t into tile load; level 2 fuses the final mean(|down2|).
//
// R2 change: register-first staging (all loads issued before any ds_write ->
// ~18 outstanding float2 loads/wave instead of ~1) to fix the latency-bound
// 25%-of-peak HBM rate seen in R1. gx0 = 64*bx-2 is 8B-aligned -> float2.

constexpr int THREADS = 256;
constexpr int TILE    = 32;            // down outputs per dim per block
constexpr int ROWS    = 2 * TILE + 3;  // 67 input rows (5x5 stencil halo)
constexpr int SEGS    = TILE + 2;      // 34 float2 segments per row (68 cols)
constexpr int STRIDE  = 2 * SEGS;      // 68-float LDS row stride
constexpr int TOT     = ROWS * SEGS;   // 2278 float2 per array per block
constexpr int SITERS  = (TOT + THREADS - 1) / THREADS;  // 9

template <bool FUSE_DIFF, bool LAST, bool WRITE_DOWN>
__global__ __launch_bounds__(THREADS)
void lap_level(const float* __restrict__ A,    // x (lvl0) or cur
               const float* __restrict__ Bp,   // t (lvl0) or nullptr
               const float* __restrict__ w25,  // 5x5 gaussian weights (channel 0)
               float* __restrict__ down,       // output H/2 x W/2 (if WRITE_DOWN)
               float* __restrict__ sums,       // sums[level], sums[3] for LAST
               int H, int W, int level)
{
    __shared__ float sd[ROWS * STRIDE];
    const int tid = threadIdx.x;
    const int ox0 = blockIdx.x * TILE;
    const int oy0 = blockIdx.y * TILE;
    const int n   = blockIdx.z;        // fused B*C image-channel index
    const size_t ibase = (size_t)n * H * W;
    const int gy0 = 2 * oy0 - 2;
    const int gx0 = 2 * ox0 - 2;       // even -> all float2 accesses 8B-aligned

    // ---- Phase A: issue ALL global loads into registers (max MLP) ----
    float2 va[SITERS], vb[SITERS];
#pragma unroll
    for (int it = 0; it < SITERS; ++it) {
        const int i = tid + it * THREADS;
        const int r = i / SEGS;
        const int s = i - r * SEGS;
        const int gy = gy0 + r;
        const int gx = gx0 + 2 * s;    // even; W even -> float2 fully in or out
        const bool ok = (i < TOT) && ((unsigned)gy < (unsigned)H)
                                  && ((unsigned)gx < (unsigned)W);
        const size_t o = ok ? (ibase + (size_t)gy * W + gx) : ibase;
        float2 a = *(const float2*)(A + o);
        float2 b = make_float2(0.0f, 0.0f);
        if (FUSE_DIFF) b = *(const float2*)(Bp + o);
        if (!ok) a = make_float2(0.0f, 0.0f);
        if (FUSE_DIFF && !ok) b = make_float2(0.0f, 0.0f);
        va[it] = a;
        if (FUSE_DIFF) vb[it] = b;
    }

    // ---- Phase B: LDS writes (waits resolve progressively, loads pipelined) ----
#pragma unroll
    for (int it = 0; it < SITERS; ++it) {
        const int i = tid + it * THREADS;
        if (i < TOT) {
            const int r = i / SEGS;
            const int s = i - r * SEGS;
            float2 d = va[it];
            if (FUSE_DIFF) { d.x -= vb[it].x; d.y -= vb[it].y; }
            *(float2*)(&sd[r * STRIDE + 2 * s]) = d;
        }
    }

    float w[25];
#pragma unroll
    for (int i = 0; i < 25; ++i) w[i] = w25[i];  // uniform -> scalar-cached

    __syncthreads();

    const int lx  = tid & (TILE - 1);  // 0..31
    const int ly0 = tid / TILE;        // 0..7
    const int Hd = H >> 1, Wd = W >> 1;
    float lsum = 0.0f;  // sum |cur - up(down)| over this thread's outputs
    float dsum = 0.0f;  // (LAST) sum |down|

#pragma unroll
    for (int k = 0; k < (TILE * TILE) / THREADS; ++k) {
        const int ly = ly0 + k * (THREADS / TILE);
        const float* row0 = &sd[(2 * ly) * STRIDE + 2 * lx];
        float acc = 0.0f;
#pragma unroll
        for (int dy = 0; dy < 5; ++dy) {
#pragma unroll
            for (int dx = 0; dx < 5; ++dx)
                acc = fmaf(w[dy * 5 + dx], row0[dy * STRIDE + dx], acc);
        }
        if (WRITE_DOWN)
            down[(size_t)n * Hd * Wd + (size_t)(oy0 + ly) * Wd + (ox0 + lx)] = acc;
        // cur pixels covered by this down value: local rows 2ly+2..3, cols 2lx+2..3
        lsum += fabsf(row0[2 * STRIDE + 2] - acc)
              + fabsf(row0[2 * STRIDE + 3] - acc)
              + fabsf(row0[3 * STRIDE + 2] - acc)
              + fabsf(row0[3 * STRIDE + 3] - acc);
        if (LAST) dsum += fabsf(acc);
    }

    // wave64 reduce, then cross-wave via LDS, one atomic per block per level
#pragma unroll
    for (int off = 32; off > 0; off >>= 1) {
        lsum += __shfl_down(lsum, off);
        if (LAST) dsum += __shfl_down(dsum, off);
    }
    __shared__ float wsum_l[THREADS / 64];
    __shared__ float wsum_d[THREADS / 64];
    const int wid = tid >> 6;
    if ((tid & 63) == 0) {
        wsum_l[wid] = lsum;
        if (LAST) wsum_d[wid] = dsum;
    }
    __syncthreads();
    if (tid == 0) {
        float s = 0.0f, s2 = 0.0f;
#pragma unroll
        for (int i = 0; i < THREADS / 64; ++i) {
            s += wsum_l[i];
            if (LAST) s2 += wsum_d[i];
        }
        atomicAdd(&sums[level], s);
        if (LAST) atomicAdd(&sums[3], s2);
    }
}

__global__ void finalize_kernel(const float* __restrict__ sums,
                                float* __restrict__ out,
                                float inv0, float inv1, float inv2, float inv3)
{
    out[0] = sums[0] * inv0 + sums[1] * inv1 + sums[2] * inv2 + sums[3] * inv3;
}

extern "C" void kernel_launch(void* const* d_in, const int* in_sizes, int n_in,
                              void* d_out, int out_size, void* d_ws, size_t ws_size,
                              hipStream_t stream)
{
    const float* x   = (const float*)d_in[0];
    const float* t   = (const float*)d_in[1];
    const float* ker = (const float*)d_in[2];  // (13,1,5,5); all channels identical
    float* out = (float*)d_out;

    constexpr int B = 16, C = 13, H = 512, W = 512;
    constexpr int N = B * C;  // 208 image-channels

    // workspace layout: [4 floats sums (pad 256B)] [down0: N*256*256] [down1: N*128*128]
    float* sums  = (float*)d_ws;
    float* down0 = (float*)((char*)d_ws + 256);
    float* down1 = down0 + (size_t)N * (H / 2) * (W / 2);

    hipMemsetAsync(sums, 0, 4 * sizeof(float), stream);

    dim3 blk(THREADS);
    // level 0: cur = x - t (fused), 512 -> down0 256
    lap_level<true, false, true><<<dim3((W/2)/TILE, (H/2)/TILE, N), blk, 0, stream>>>(
        x, t, ker, down0, sums, H, W, 0);
    // level 1: down0 256 -> down1 128
    lap_level<false, false, true><<<dim3((W/4)/TILE, (H/4)/TILE, N), blk, 0, stream>>>(
        down0, nullptr, ker, down1, sums, H / 2, W / 2, 1);
    // level 2: down1 128 -> (64, kept in-register), fuses level-3 mean(|down2|)
    lap_level<false, true, false><<<dim3((W/8)/TILE, (H/8)/TILE, N), blk, 0, stream>>>(
        down1, nullptr, ker, nullptr, sums, H / 4, W / 4, 2);

    const float inv0 = 1.0f / ((float)N * H * W);
    const float inv1 = 1.0f / ((float)N * (H/2) * (W/2));
    const float inv2 = 1.0f / ((float)N * (H/4) * (W/4));
    const float inv3 = 1.0f / ((float)N * (H/8) * (W/8));
    finalize_kernel<<<1, 1, 0, stream>>>(sums, out, inv0, inv1, inv2, inv3);
}